// Round 8
// baseline (207.344 us; speedup 1.0000x reference)
//
#include <hip/hip_runtime.h>
#include <hip/hip_bf16.h>
#include <math.h>

// RecursivePriorStateSpace: B=8, C=HID=256, H=W=128.
// Pipeline:
//   kw  : Wi f32 -> bf16 ; Wo f32 -> fp8-e4m3
//   k01 : x,prior --(F_mod, in-LDS transpose)--> GEMM1(bf16 MFMA) --> u fp8
//         + fused h-scan -> hh fp8   (fp8 intermediates: error ~1e-3 << 0.109 thr)
//   k2v : hf(fp8) = hh + scan_h(u)   (scalar 1-chain/thread, 4096 waves, TLP-bound)
//   k3  : out[b][o][p] = x + a*clip(prior) + g*(Wo @ hf^T + bo)
//         FP8 MFMA (mfma_f32_16x16x32_fp8_fp8), pure gload_lds staging (fp8 bytes),
//         LDS 24 KB. Same fragment index math as bf16 (shape-determined C/D layout).
// ws: [0,32M) u fp8 ; [32M,64M) hh fp8 ; [64M,96M) hf fp8 ; then Wi_bf16, Wo_fp8.

typedef unsigned int u32;
typedef unsigned short u16;
typedef unsigned char u8;
typedef long i64;
typedef __bf16 bf16x8 __attribute__((ext_vector_type(8)));
typedef float f32x4 __attribute__((ext_vector_type(4)));

__device__ __forceinline__ float bf2f(u16 r) { return __uint_as_float(((u32)r) << 16); }
__device__ __forceinline__ u16 f2bf(float f) {
    u32 x = __float_as_uint(f);
    return (u16)((x + 0x7FFFu + ((x >> 16) & 1u)) >> 16);  // RNE
}
__device__ __forceinline__ float clip1(float v) { return fminf(1.f, fmaxf(-1.f, v)); }
__device__ __forceinline__ u8 f2fp8(float v) {
    return (u8)(__builtin_amdgcn_cvt_pk_fp8_f32(v, v, 0, false) & 0xFF);
}
__device__ __forceinline__ float fp82f(u32 byte) {
    return __builtin_amdgcn_cvt_f32_fp8(byte, 0);
}

__device__ __forceinline__ void gload16(const void* g, void* l) {
    __builtin_amdgcn_global_load_lds((__attribute__((address_space(1))) void*)g,
                                     (__attribute__((address_space(3))) void*)l, 16, 0, 0);
}

// ---------------- kw: Wi -> bf16, Wo -> fp8 ----------------
__global__ __launch_bounds__(256) void kw_conv(const float* __restrict__ Wi,
                                               const float* __restrict__ Wo,
                                               u16* __restrict__ Wib, u8* __restrict__ Wo8) {
    int i = blockIdx.x * 256 + threadIdx.x;
    Wib[i] = f2bf(Wi[i]);
    Wo8[i] = f2fp8(Wo[i]);
}

// ---------------- k01: fused F_mod + transpose + GEMM1 + h-scan ----------------
// Block = (b, h): one image row (128 pixels), all 256 o.  512 threads = 8 waves.
// GEMM: M=128 (w), N=256 (o), K=256 (c), BK=32, 8 K-steps, 1 barrier/step.
#define SA_STRIDE 40  // u16 elems per row (80 B): 16B-aligned frag reads, spread banks
__global__ __launch_bounds__(512) void k01_gemm1(const float* __restrict__ x,
                                                 const float* __restrict__ prior,
                                                 const u16* __restrict__ Wib,
                                                 const float* __restrict__ bi,
                                                 const float* __restrict__ Bp,
                                                 const float* __restrict__ A_param,
                                                 const float* __restrict__ alpha_p,
                                                 u8* __restrict__ u8p, u8* __restrict__ hh8p) {
    __shared__ __align__(16) char smem[65536];
    u16* sA = (u16*)smem;              // [2][128*SA_STRIDE] = 20480 B  (F_mod tile, [w][c])
    u16* sB = (u16*)(smem + 20480);    // [2][256*32]        = 32768 B  (Wi tile, [o][c])
    u16* ut = (u16*)smem;              // epilogue: u tile [128w][256o] bf16 = 64 KiB

    const int t = threadIdx.x;
    const int b = blockIdx.x >> 7, h = blockIdx.x & 127;
    const int wave = t >> 6, l = t & 63;
    const int wr = wave >> 2, wc = wave & 3;   // 2 x 4 wave grid over (w, o)
    const int lr = l & 15, lg = l >> 4;

    // x-staging thread map: c = t&31 (per K-step local), w-range = (t>>5)*8 .. +7
    const int cl = t & 31, w0 = (t >> 5) * 8;
    const float alpha = alpha_p[0];

    // precompute alpha*clip(prior) for this thread's 8 w's (constant across K-steps)
    const float* prow = prior + (size_t)b * 16384 + h * 128 + w0;
    float fp[8];
    {
        float4 p0 = *(const float4*)prow;
        float4 p1 = *(const float4*)(prow + 4);
        fp[0] = alpha * clip1(p0.x); fp[1] = alpha * clip1(p0.y);
        fp[2] = alpha * clip1(p0.z); fp[3] = alpha * clip1(p0.w);
        fp[4] = alpha * clip1(p1.x); fp[5] = alpha * clip1(p1.y);
        fp[6] = alpha * clip1(p1.z); fp[7] = alpha * clip1(p1.w);
    }
    // x row base for (b, h): element (c, w) at xrow + c*16384 + w
    const float* xrow = x + ((size_t)b * 256 * 128 + h) * 128;

    f32x4 acc[4][4];
#pragma unroll
    for (int mi = 0; mi < 4; ++mi)
#pragma unroll
        for (int ni = 0; ni < 4; ++ni) acc[mi][ni] = (f32x4){0.f, 0.f, 0.f, 0.f};

    float4 xa, xb;
#define LOADX(ks)                                                        \
    do {                                                                 \
        const float* p_ = xrow + (size_t)((ks) * 32 + cl) * 16384 + w0;  \
        xa = *(const float4*)p_;                                         \
        xb = *(const float4*)(p_ + 4);                                   \
    } while (0)
#define CVTWR(buf)                                            \
    do {                                                      \
        u16* d_ = sA + (buf) * (128 * SA_STRIDE);             \
        d_[(w0 + 0) * SA_STRIDE + cl] = f2bf(xa.x + fp[0]);   \
        d_[(w0 + 1) * SA_STRIDE + cl] = f2bf(xa.y + fp[1]);   \
        d_[(w0 + 2) * SA_STRIDE + cl] = f2bf(xa.z + fp[2]);   \
        d_[(w0 + 3) * SA_STRIDE + cl] = f2bf(xa.w + fp[3]);   \
        d_[(w0 + 4) * SA_STRIDE + cl] = f2bf(xb.x + fp[4]);   \
        d_[(w0 + 5) * SA_STRIDE + cl] = f2bf(xb.y + fp[5]);   \
        d_[(w0 + 6) * SA_STRIDE + cl] = f2bf(xb.z + fp[6]);   \
        d_[(w0 + 7) * SA_STRIDE + cl] = f2bf(xb.w + fp[7]);   \
    } while (0)
#define STAGEB(buf, ks)                                                                     \
    do {                                                                                    \
        const int k0_ = (ks) * 32;                                                          \
        { const int s = t;                                                                  \
          gload16(&Wib[(size_t)(s >> 2) * 256 + k0_ + (s & 3) * 8],                         \
                  sB + (buf) * 8192 + s * 8); }                                             \
        { const int s = t + 512;                                                            \
          gload16(&Wib[(size_t)(s >> 2) * 256 + k0_ + (s & 3) * 8],                         \
                  sB + (buf) * 8192 + s * 8); }                                             \
    } while (0)

    // prologue: stage step 0
    LOADX(0);
    STAGEB(0, 0);
    CVTWR(0);
    __syncthreads();

    int cur = 0;
    for (int ks = 0; ks < 8; ++ks) {
        if (ks < 7) {
            LOADX(ks + 1);          // global->reg, hides under MFMA below
            STAGEB(cur ^ 1, ks + 1);
        }
        bf16x8 af[4], bfv[4];
#pragma unroll
        for (int mi = 0; mi < 4; ++mi)
            af[mi] = *(const bf16x8*)&sA[cur * (128 * SA_STRIDE) +
                                         (wr * 64 + mi * 16 + lr) * SA_STRIDE + lg * 8];
#pragma unroll
        for (int ni = 0; ni < 4; ++ni)
            bfv[ni] = *(const bf16x8*)&sB[cur * 8192 + (wc * 64 + ni * 16 + lr) * 32 + lg * 8];
#pragma unroll
        for (int mi = 0; mi < 4; ++mi)
#pragma unroll
            for (int ni = 0; ni < 4; ++ni)
                acc[mi][ni] =
                    __builtin_amdgcn_mfma_f32_16x16x32_bf16(af[mi], bfv[ni], acc[mi][ni], 0, 0, 0);
        if (ks < 7) CVTWR(cur ^ 1);  // consumes xa/xb (vmcnt wait auto-inserted)
        __syncthreads();             // drains ds_writes + gload_lds before next compute
        cur ^= 1;
    }
#undef LOADX
#undef CVTWR
#undef STAGEB

    // ---- epilogue: acc -> ut (bf16, with Bp/bi fused), then h-scan ----
    // (loop above ended with a barrier, safe to overwrite sA/sB alias)
    float bp4[4], bi4[4];
#pragma unroll
    for (int ni = 0; ni < 4; ++ni) {
        const int o = wc * 64 + ni * 16 + lr;
        bp4[ni] = Bp[o];
        bi4[ni] = bi[o];
    }
#pragma unroll
    for (int mi = 0; mi < 4; ++mi)
#pragma unroll
        for (int j = 0; j < 4; ++j) {
            const int w = wr * 64 + mi * 16 + lg * 4 + j;  // D row = w
#pragma unroll
            for (int ni = 0; ni < 4; ++ni) {
                const int o = wc * 64 + ni * 16 + lr;      // D col = o
                ut[w * 256 + o] = f2bf(bp4[ni] * (acc[mi][ni][j] + bi4[ni]));
            }
        }
    __syncthreads();

    const size_t gbase = ((size_t)b * 16384 + (size_t)h * 128) * 256;  // elem index
    if (wave < 4) {
        // waves 0-3: h-scan over w (256 chains, one per o), write hh as fp8
        const int o = t;  // 0..255
        const float A = tanhf(A_param[o]);
        float hacc = 0.f;
        u8* hhp = hh8p + gbase + o;
        for (int wb = 0; wb < 16; ++wb) {
            float v[8];
#pragma unroll
            for (int j = 0; j < 8; ++j) v[j] = bf2f(ut[(wb * 8 + j) * 256 + o]);
            u8 s8[8];
#pragma unroll
            for (int j = 0; j < 8; ++j) {
                hacc = fmaf(A, hacc, v[j]);
                s8[j] = f2fp8(hacc);
            }
#pragma unroll
            for (int j = 0; j < 8; ++j) hhp[(size_t)(wb * 8 + j) * 256] = s8[j];
        }
    } else {
        // waves 4-7: ut (bf16 LDS) -> u (global, fp8), coalesced 8B chunks
        const int t2 = t - 256;  // 0..255
        uint2* ug = (uint2*)(u8p + gbase);
        const int4* us = (const int4*)ut;
#pragma unroll
        for (int i = 0; i < 16; ++i) {
            const int chunk = t2 + 256 * i;  // 4096 chunks x (8 bf16 -> 8 fp8)
            const int4 v = us[chunk];
            const float f0 = bf2f((u16)(v.x & 0xFFFF)), f1 = bf2f((u16)((u32)v.x >> 16));
            const float f2 = bf2f((u16)(v.y & 0xFFFF)), f3 = bf2f((u16)((u32)v.y >> 16));
            const float f4 = bf2f((u16)(v.z & 0xFFFF)), f5 = bf2f((u16)((u32)v.z >> 16));
            const float f6 = bf2f((u16)(v.w & 0xFFFF)), f7 = bf2f((u16)((u32)v.w >> 16));
            u32 lo = (u32)__builtin_amdgcn_cvt_pk_fp8_f32(f0, f1, 0, false);
            lo = (u32)__builtin_amdgcn_cvt_pk_fp8_f32(f2, f3, (int)lo, true);
            u32 hi = (u32)__builtin_amdgcn_cvt_pk_fp8_f32(f4, f5, 0, false);
            hi = (u32)__builtin_amdgcn_cvt_pk_fp8_f32(f6, f7, (int)hi, true);
            ug[chunk] = make_uint2(lo, hi);
        }
    }
}

// ---------------- k2v: hf(fp8) = hh + scan_h(u), fp8 in/out ----------------
// Block=(b,w) grid 1024, thread=o (256): 1 chain/thread (TLP-bound; 4096 waves).
__global__ __launch_bounds__(256) void k2v(const u8* __restrict__ u8p,
                                           const u8* __restrict__ hh8p,
                                           u8* __restrict__ hf8,
                                           const float* __restrict__ A_param) {
    const int o = threadIdx.x;
    const int b = blockIdx.x >> 7, w = blockIdx.x & 127;
    const float A = tanhf(A_param[o]);
    size_t base = ((size_t)b * 16384 + w) * 256 + o;
    float hacc = 0.f;
    for (int hb = 0; hb < 16; ++hb) {
        u32 v[8], g[8];
#pragma unroll
        for (int j = 0; j < 8; ++j) {
            v[j] = u8p[base + (size_t)j * 32768];
            g[j] = hh8p[base + (size_t)j * 32768];
        }
        u8 w8[8];
#pragma unroll
        for (int j = 0; j < 8; ++j) {
            hacc = fmaf(A, hacc, fp82f(v[j]));
            w8[j] = f2fp8(hacc + fp82f(g[j]));
        }
#pragma unroll
        for (int j = 0; j < 8; ++j) hf8[base + (size_t)j * 32768] = w8[j];
        base += (size_t)8 * 32768;
    }
}

// ---------------- k3: FP8 GEMM2 + epilogue. out = x + a*clip(prior) + g*(Wo@hf + bo) ----
// BM=256 (o), BN=128 (pixels), BK=32, 512 threads = 8 waves (wr 0..3, wc 0..1).
// mfma_f32_16x16x32_fp8_fp8: 8 fp8/lane fragments (i64), same (lr,lg) index math,
// same shape-determined C/D layout. Pure gload_lds staging (fp8 bytes), LDS 24 KB.
__global__ __launch_bounds__(512) void k3_gemm2(const u8* __restrict__ hf8,
                                                const u8* __restrict__ Wo8,
                                                const float* __restrict__ x,
                                                const float* __restrict__ prior,
                                                const float* __restrict__ bo,
                                                const float* __restrict__ alpha_p,
                                                const float* __restrict__ gamma_p,
                                                float* __restrict__ out) {
    __shared__ __align__(16) u8 sA[2][256 * 32];  // Wo tile [256o][32h] fp8
    __shared__ __align__(16) u8 sB[2][128 * 32];  // hf tile [128p][32h] fp8
    const int t = threadIdx.x;
    const int bx = blockIdx.x;  // b*128 + nt
    const int b = bx >> 7, nt = bx & 127;
    const size_t Hbase = ((size_t)b * 16384 + (size_t)nt * 128) * 256;
    const int wave = t >> 6, l = t & 63;
    const int wr = wave >> 1, wc = wave & 1;
    const int lr = l & 15, lg = l >> 4;

    f32x4 acc[4][4];
#pragma unroll
    for (int mi = 0; mi < 4; ++mi)
#pragma unroll
        for (int ni = 0; ni < 4; ++ni) acc[mi][ni] = (f32x4){0.f, 0.f, 0.f, 0.f};

    // A-tile: 256 rows x 32 fp8 = 8192 B = 512 lanes x 16 B (all threads).
    // B-tile: 128 rows x 32 fp8 = 4096 B = 256 lanes x 16 B (waves 0-3 only).
#define STAGE3(buf, ks)                                                                    \
    do {                                                                                   \
        const int k0_ = (ks) * 32;                                                         \
        { const int s = t;                                                                 \
          gload16(&Wo8[(size_t)(s >> 1) * 256 + k0_ + (s & 1) * 16], &sA[buf][s * 16]); }  \
        if (t < 256) {                                                                     \
            const int s = t;                                                               \
            gload16(&hf8[Hbase + (size_t)(s >> 1) * 256 + k0_ + (s & 1) * 16],             \
                    &sB[buf][s * 16]);                                                     \
        }                                                                                  \
    } while (0)

    int cur = 0;
    STAGE3(0, 0);
    __syncthreads();
    for (int ks = 0; ks < 8; ++ks) {
        if (ks < 7) STAGE3(cur ^ 1, ks + 1);
        i64 af[4], bfv[4];
#pragma unroll
        for (int mi = 0; mi < 4; ++mi)
            af[mi] = *(const i64*)&sA[cur][(wr * 64 + mi * 16 + lr) * 32 + lg * 8];
#pragma unroll
        for (int ni = 0; ni < 4; ++ni)
            bfv[ni] = *(const i64*)&sB[cur][(wc * 64 + ni * 16 + lr) * 32 + lg * 8];
#pragma unroll
        for (int mi = 0; mi < 4; ++mi)
#pragma unroll
            for (int ni = 0; ni < 4; ++ni)
                acc[mi][ni] = __builtin_amdgcn_mfma_f32_16x16x32_fp8_fp8(af[mi], bfv[ni],
                                                                         acc[mi][ni], 0, 0, 0);
        __syncthreads();
        cur ^= 1;
    }
#undef STAGE3

    const float alpha = alpha_p[0], gamma = gamma_p[0];
    float pr4[4];
#pragma unroll
    for (int ni = 0; ni < 4; ++ni) {
        const int p_loc = wc * 64 + ni * 16 + lr;
        pr4[ni] = clip1(prior[(size_t)b * 16384 + (size_t)nt * 128 + p_loc]);
    }
#pragma unroll
    for (int mi = 0; mi < 4; ++mi)
#pragma unroll
        for (int j = 0; j < 4; ++j) {
            const int o = wr * 64 + mi * 16 + lg * 4 + j;  // D row = o
            const float bov = bo[o];
            const size_t obase = ((size_t)b * 256 + o) * 16384 + (size_t)nt * 128;
#pragma unroll
            for (int ni = 0; ni < 4; ++ni) {
                const int p_loc = wc * 64 + ni * 16 + lr;  // D col = pixel
                out[obase + p_loc] =
                    x[obase + p_loc] + alpha * pr4[ni] + gamma * (acc[mi][ni][j] + bov);
            }
        }
}

extern "C" void kernel_launch(void* const* d_in, const int* in_sizes, int n_in,
                              void* d_out, int out_size, void* d_ws, size_t ws_size,
                              hipStream_t stream) {
    const float* x = (const float*)d_in[0];
    const float* prior = (const float*)d_in[1];
    const float* Wi = (const float*)d_in[2];
    const float* bi = (const float*)d_in[3];
    const float* A_param = (const float*)d_in[4];
    const float* B_param = (const float*)d_in[5];
    const float* alpha = (const float*)d_in[6];
    const float* gamma = (const float*)d_in[7];
    const float* Wo = (const float*)d_in[8];
    const float* bo = (const float*)d_in[9];
    float* out = (float*)d_out;

    u8* u8p = (u8*)d_ws;                             // 32 MiB fp8 u
    u8* hh8p = (u8*)d_ws + 33554432ull;              // 32 MiB fp8 hh
    u8* hf8 = (u8*)d_ws + 67108864ull;               // 32 MiB fp8 hf
    u16* Wib = (u16*)((char*)d_ws + 134217728ull);   // 128 KiB bf16 Wi
    u8* Wo8 = (u8*)d_ws + 134348800ull;              // 64 KiB fp8 Wo

    hipLaunchKernelGGL(kw_conv, dim3(256), dim3(256), 0, stream, Wi, Wo, Wib, Wo8);
    hipLaunchKernelGGL(k01_gemm1, dim3(1024), dim3(512), 0, stream, x, prior, Wib, bi, B_param,
                       A_param, alpha, u8p, hh8p);
    hipLaunchKernelGGL(k2v, dim3(1024), dim3(256), 0, stream, u8p, hh8p, hf8, A_param);
    hipLaunchKernelGGL(k3_gemm2, dim3(1024), dim3(512), 0, stream, hf8, Wo8, x, prior, bo,
                       alpha, gamma, out);
}

// Round 9
// 160.824 us; speedup vs baseline: 1.2893x; 1.2893x over previous
//
#include <hip/hip_runtime.h>
#include <hip/hip_bf16.h>
#include <math.h>

// RecursivePriorStateSpace: B=8, C=HID=256, H=W=128.
// Pipeline:
//   kw  : Wi,Wo f32 -> bf16
//   k01 : x,prior --(F_mod, in-LDS transpose)--> GEMM1(bf16 MFMA) --> u fp8
//         + fused h-scan -> hh fp8   (fp8 intermediates: error ~1e-3 << 0.109 thr)
//   k2v : hf(bf16) = hh + scan_h(u)  (scalar 1-chain/thread, 4096 waves, TLP-bound)
//   k3  : out[b][o][p] = x + a*clip(prior) + g*(Wo @ hf^T + bo)
//         bf16 MFMA, pure gload_lds staging. (R8 lesson: fp8 MFMA k3 regressed
//         84->146us -- 32B LDS rows made b64 frag reads a 4-way bank conflict,
//         SQ_LDS_BANK_CONFLICT 2.1M->6.3M. bf16 64B rows = 2-way = free.)
// ws: [0,32M) u fp8 ; [32M,64M) hh fp8 ; [64M,128M) hf bf16 ; then Wi_bf16, Wo_bf16.

typedef unsigned int u32;
typedef unsigned short u16;
typedef unsigned char u8;
typedef __bf16 bf16x8 __attribute__((ext_vector_type(8)));
typedef float f32x4 __attribute__((ext_vector_type(4)));

__device__ __forceinline__ float bf2f(u16 r) { return __uint_as_float(((u32)r) << 16); }
__device__ __forceinline__ u16 f2bf(float f) {
    u32 x = __float_as_uint(f);
    return (u16)((x + 0x7FFFu + ((x >> 16) & 1u)) >> 16);  // RNE
}
__device__ __forceinline__ float clip1(float v) { return fminf(1.f, fmaxf(-1.f, v)); }
__device__ __forceinline__ u8 f2fp8(float v) {
    return (u8)(__builtin_amdgcn_cvt_pk_fp8_f32(v, v, 0, false) & 0xFF);
}
__device__ __forceinline__ float fp82f(u32 byte) {
    return __builtin_amdgcn_cvt_f32_fp8(byte, 0);
}

__device__ __forceinline__ void gload16(const void* g, void* l) {
    __builtin_amdgcn_global_load_lds((__attribute__((address_space(1))) void*)g,
                                     (__attribute__((address_space(3))) void*)l, 16, 0, 0);
}

// ---------------- kw: weight f32 -> bf16 ----------------
__global__ __launch_bounds__(256) void kw_conv(const float* __restrict__ Wi,
                                               const float* __restrict__ Wo,
                                               u16* __restrict__ Wib, u16* __restrict__ Wob) {
    int i = blockIdx.x * 256 + threadIdx.x;
    Wib[i] = f2bf(Wi[i]);
    Wob[i] = f2bf(Wo[i]);
}

// ---------------- k01: fused F_mod + transpose + GEMM1 + h-scan ----------------
// Block = (b, h): one image row (128 pixels), all 256 o.  512 threads = 8 waves.
// GEMM: M=128 (w), N=256 (o), K=256 (c), BK=32, 8 K-steps, 1 barrier/step.
#define SA_STRIDE 40  // u16 elems per row (80 B): 16B-aligned frag reads, spread banks
__global__ __launch_bounds__(512) void k01_gemm1(const float* __restrict__ x,
                                                 const float* __restrict__ prior,
                                                 const u16* __restrict__ Wib,
                                                 const float* __restrict__ bi,
                                                 const float* __restrict__ Bp,
                                                 const float* __restrict__ A_param,
                                                 const float* __restrict__ alpha_p,
                                                 u8* __restrict__ u8p, u8* __restrict__ hh8p) {
    __shared__ __align__(16) char smem[65536];
    u16* sA = (u16*)smem;              // [2][128*SA_STRIDE] = 20480 B  (F_mod tile, [w][c])
    u16* sB = (u16*)(smem + 20480);    // [2][256*32]        = 32768 B  (Wi tile, [o][c])
    u16* ut = (u16*)smem;              // epilogue: u tile [128w][256o] bf16 = 64 KiB

    const int t = threadIdx.x;
    const int b = blockIdx.x >> 7, h = blockIdx.x & 127;
    const int wave = t >> 6, l = t & 63;
    const int wr = wave >> 2, wc = wave & 3;   // 2 x 4 wave grid over (w, o)
    const int lr = l & 15, lg = l >> 4;

    // x-staging thread map: c = t&31 (per K-step local), w-range = (t>>5)*8 .. +7
    const int cl = t & 31, w0 = (t >> 5) * 8;
    const float alpha = alpha_p[0];

    // precompute alpha*clip(prior) for this thread's 8 w's (constant across K-steps)
    const float* prow = prior + (size_t)b * 16384 + h * 128 + w0;
    float fp[8];
    {
        float4 p0 = *(const float4*)prow;
        float4 p1 = *(const float4*)(prow + 4);
        fp[0] = alpha * clip1(p0.x); fp[1] = alpha * clip1(p0.y);
        fp[2] = alpha * clip1(p0.z); fp[3] = alpha * clip1(p0.w);
        fp[4] = alpha * clip1(p1.x); fp[5] = alpha * clip1(p1.y);
        fp[6] = alpha * clip1(p1.z); fp[7] = alpha * clip1(p1.w);
    }
    // x row base for (b, h): element (c, w) at xrow + c*16384 + w
    const float* xrow = x + ((size_t)b * 256 * 128 + h) * 128;

    f32x4 acc[4][4];
#pragma unroll
    for (int mi = 0; mi < 4; ++mi)
#pragma unroll
        for (int ni = 0; ni < 4; ++ni) acc[mi][ni] = (f32x4){0.f, 0.f, 0.f, 0.f};

    float4 xa, xb;
#define LOADX(ks)                                                        \
    do {                                                                 \
        const float* p_ = xrow + (size_t)((ks) * 32 + cl) * 16384 + w0;  \
        xa = *(const float4*)p_;                                         \
        xb = *(const float4*)(p_ + 4);                                   \
    } while (0)
#define CVTWR(buf)                                            \
    do {                                                      \
        u16* d_ = sA + (buf) * (128 * SA_STRIDE);             \
        d_[(w0 + 0) * SA_STRIDE + cl] = f2bf(xa.x + fp[0]);   \
        d_[(w0 + 1) * SA_STRIDE + cl] = f2bf(xa.y + fp[1]);   \
        d_[(w0 + 2) * SA_STRIDE + cl] = f2bf(xa.z + fp[2]);   \
        d_[(w0 + 3) * SA_STRIDE + cl] = f2bf(xa.w + fp[3]);   \
        d_[(w0 + 4) * SA_STRIDE + cl] = f2bf(xb.x + fp[4]);   \
        d_[(w0 + 5) * SA_STRIDE + cl] = f2bf(xb.y + fp[5]);   \
        d_[(w0 + 6) * SA_STRIDE + cl] = f2bf(xb.z + fp[6]);   \
        d_[(w0 + 7) * SA_STRIDE + cl] = f2bf(xb.w + fp[7]);   \
    } while (0)
#define STAGEB(buf, ks)                                                                     \
    do {                                                                                    \
        const int k0_ = (ks) * 32;                                                          \
        { const int s = t;                                                                  \
          gload16(&Wib[(size_t)(s >> 2) * 256 + k0_ + (s & 3) * 8],                         \
                  sB + (buf) * 8192 + s * 8); }                                             \
        { const int s = t + 512;                                                            \
          gload16(&Wib[(size_t)(s >> 2) * 256 + k0_ + (s & 3) * 8],                         \
                  sB + (buf) * 8192 + s * 8); }                                             \
    } while (0)

    // prologue: stage step 0
    LOADX(0);
    STAGEB(0, 0);
    CVTWR(0);
    __syncthreads();

    int cur = 0;
    for (int ks = 0; ks < 8; ++ks) {
        if (ks < 7) {
            LOADX(ks + 1);          // global->reg, hides under MFMA below
            STAGEB(cur ^ 1, ks + 1);
        }
        bf16x8 af[4], bfv[4];
#pragma unroll
        for (int mi = 0; mi < 4; ++mi)
            af[mi] = *(const bf16x8*)&sA[cur * (128 * SA_STRIDE) +
                                         (wr * 64 + mi * 16 + lr) * SA_STRIDE + lg * 8];
#pragma unroll
        for (int ni = 0; ni < 4; ++ni)
            bfv[ni] = *(const bf16x8*)&sB[cur * 8192 + (wc * 64 + ni * 16 + lr) * 32 + lg * 8];
#pragma unroll
        for (int mi = 0; mi < 4; ++mi)
#pragma unroll
            for (int ni = 0; ni < 4; ++ni)
                acc[mi][ni] =
                    __builtin_amdgcn_mfma_f32_16x16x32_bf16(af[mi], bfv[ni], acc[mi][ni], 0, 0, 0);
        if (ks < 7) CVTWR(cur ^ 1);  // consumes xa/xb (vmcnt wait auto-inserted)
        __syncthreads();             // drains ds_writes + gload_lds before next compute
        cur ^= 1;
    }
#undef LOADX
#undef CVTWR
#undef STAGEB

    // ---- epilogue: acc -> ut (bf16, with Bp/bi fused), then h-scan ----
    // (loop above ended with a barrier, safe to overwrite sA/sB alias)
    float bp4[4], bi4[4];
#pragma unroll
    for (int ni = 0; ni < 4; ++ni) {
        const int o = wc * 64 + ni * 16 + lr;
        bp4[ni] = Bp[o];
        bi4[ni] = bi[o];
    }
#pragma unroll
    for (int mi = 0; mi < 4; ++mi)
#pragma unroll
        for (int j = 0; j < 4; ++j) {
            const int w = wr * 64 + mi * 16 + lg * 4 + j;  // D row = w
#pragma unroll
            for (int ni = 0; ni < 4; ++ni) {
                const int o = wc * 64 + ni * 16 + lr;      // D col = o
                ut[w * 256 + o] = f2bf(bp4[ni] * (acc[mi][ni][j] + bi4[ni]));
            }
        }
    __syncthreads();

    const size_t gbase = ((size_t)b * 16384 + (size_t)h * 128) * 256;  // elem index
    if (wave < 4) {
        // waves 0-3: h-scan over w (256 chains, one per o), write hh as fp8
        const int o = t;  // 0..255
        const float A = tanhf(A_param[o]);
        float hacc = 0.f;
        u8* hhp = hh8p + gbase + o;
        for (int wb = 0; wb < 16; ++wb) {
            float v[8];
#pragma unroll
            for (int j = 0; j < 8; ++j) v[j] = bf2f(ut[(wb * 8 + j) * 256 + o]);
            u8 s8[8];
#pragma unroll
            for (int j = 0; j < 8; ++j) {
                hacc = fmaf(A, hacc, v[j]);
                s8[j] = f2fp8(hacc);
            }
#pragma unroll
            for (int j = 0; j < 8; ++j) hhp[(size_t)(wb * 8 + j) * 256] = s8[j];
        }
    } else {
        // waves 4-7: ut (bf16 LDS) -> u (global, fp8), coalesced 8B chunks
        const int t2 = t - 256;  // 0..255
        uint2* ug = (uint2*)(u8p + gbase);
        const int4* us = (const int4*)ut;
#pragma unroll
        for (int i = 0; i < 16; ++i) {
            const int chunk = t2 + 256 * i;  // 4096 chunks x (8 bf16 -> 8 fp8)
            const int4 v = us[chunk];
            const float f0 = bf2f((u16)(v.x & 0xFFFF)), f1 = bf2f((u16)((u32)v.x >> 16));
            const float f2 = bf2f((u16)(v.y & 0xFFFF)), f3 = bf2f((u16)((u32)v.y >> 16));
            const float f4 = bf2f((u16)(v.z & 0xFFFF)), f5 = bf2f((u16)((u32)v.z >> 16));
            const float f6 = bf2f((u16)(v.w & 0xFFFF)), f7 = bf2f((u16)((u32)v.w >> 16));
            u32 lo = (u32)__builtin_amdgcn_cvt_pk_fp8_f32(f0, f1, 0, false);
            lo = (u32)__builtin_amdgcn_cvt_pk_fp8_f32(f2, f3, (int)lo, true);
            u32 hi = (u32)__builtin_amdgcn_cvt_pk_fp8_f32(f4, f5, 0, false);
            hi = (u32)__builtin_amdgcn_cvt_pk_fp8_f32(f6, f7, (int)hi, true);
            ug[chunk] = make_uint2(lo, hi);
        }
    }
}

// ---------------- k2v: hf(bf16) = hh + scan_h(u), fp8 inputs ----------------
// Block=(b,w) grid 1024, thread=o (256): 1 chain/thread (TLP-bound: 4096 waves =
// 16/CU is the max the 262144 fixed-length chains allow; measured fastest).
__global__ __launch_bounds__(256) void k2v(const u8* __restrict__ u8p,
                                           const u8* __restrict__ hh8p,
                                           u16* __restrict__ hf,
                                           const float* __restrict__ A_param) {
    const int o = threadIdx.x;
    const int b = blockIdx.x >> 7, w = blockIdx.x & 127;
    const float A = tanhf(A_param[o]);
    size_t base = ((size_t)b * 16384 + w) * 256 + o;
    float hacc = 0.f;
    for (int hb = 0; hb < 16; ++hb) {
        u32 v[8], g[8];
#pragma unroll
        for (int j = 0; j < 8; ++j) {
            v[j] = u8p[base + (size_t)j * 32768];
            g[j] = hh8p[base + (size_t)j * 32768];
        }
        u16 w8[8];
#pragma unroll
        for (int j = 0; j < 8; ++j) {
            hacc = fmaf(A, hacc, fp82f(v[j]));
            w8[j] = f2bf(hacc + fp82f(g[j]));
        }
#pragma unroll
        for (int j = 0; j < 8; ++j) hf[base + (size_t)j * 32768] = w8[j];
        base += (size_t)8 * 32768;
    }
}

// ---------------- k3: GEMM2 + epilogue. out[b][o][p] = x + a*clip(prior) + g*(Wo@hf + bo) ----
// BM=256 (o, full), BN=128 (pixels), BK=32, 512 threads = 8 waves (wr 0..3, wc 0..1).
// Pure gload_lds staging for both tiles (known-good structure, k3 ~= write floor).
__global__ __launch_bounds__(512) void k3_gemm2(const u16* __restrict__ hf,
                                                const u16* __restrict__ Wob,
                                                const float* __restrict__ x,
                                                const float* __restrict__ prior,
                                                const float* __restrict__ bo,
                                                const float* __restrict__ alpha_p,
                                                const float* __restrict__ gamma_p,
                                                float* __restrict__ out) {
    __shared__ __align__(16) u16 sA[2][256 * 32];  // Wo tile [256o][32h]
    __shared__ __align__(16) u16 sB[2][128 * 32];  // hf tile [128p][32h]
    const int t = threadIdx.x;
    const int bx = blockIdx.x;  // b*128 + nt
    const int b = bx >> 7, nt = bx & 127;
    const size_t Hbase = ((size_t)b * 16384 + (size_t)nt * 128) * 256;
    const int wave = t >> 6, l = t & 63;
    const int wr = wave >> 1, wc = wave & 1;
    const int lr = l & 15, lg = l >> 4;

    f32x4 acc[4][4];
#pragma unroll
    for (int mi = 0; mi < 4; ++mi)
#pragma unroll
        for (int ni = 0; ni < 4; ++ni) acc[mi][ni] = (f32x4){0.f, 0.f, 0.f, 0.f};

#define STAGE3(buf, ks)                                                                   \
    do {                                                                                  \
        const int k0_ = (ks) * 32;                                                        \
        { const int s = t;                                                                \
          gload16(&Wob[(size_t)(s >> 2) * 256 + k0_ + (s & 3) * 8], &sA[buf][s * 8]); }   \
        { const int s = t + 512;                                                          \
          gload16(&Wob[(size_t)(s >> 2) * 256 + k0_ + (s & 3) * 8], &sA[buf][s * 8]); }   \
        { const int s = t;                                                                \
          gload16(&hf[Hbase + (size_t)(s >> 2) * 256 + k0_ + (s & 3) * 8],                \
                  &sB[buf][s * 8]); }                                                     \
    } while (0)

    int cur = 0;
    STAGE3(0, 0);
    __syncthreads();
    for (int ks = 0; ks < 8; ++ks) {
        if (ks < 7) STAGE3(cur ^ 1, ks + 1);
        bf16x8 af[4], bfv[4];
#pragma unroll
        for (int mi = 0; mi < 4; ++mi)
            af[mi] = *(const bf16x8*)&sA[cur][(wr * 64 + mi * 16 + lr) * 32 + lg * 8];
#pragma unroll
        for (int ni = 0; ni < 4; ++ni)
            bfv[ni] = *(const bf16x8*)&sB[cur][(wc * 64 + ni * 16 + lr) * 32 + lg * 8];
#pragma unroll
        for (int mi = 0; mi < 4; ++mi)
#pragma unroll
            for (int ni = 0; ni < 4; ++ni)
                acc[mi][ni] =
                    __builtin_amdgcn_mfma_f32_16x16x32_bf16(af[mi], bfv[ni], acc[mi][ni], 0, 0, 0);
        __syncthreads();
        cur ^= 1;
    }
#undef STAGE3

    const float alpha = alpha_p[0], gamma = gamma_p[0];
    float pr4[4];
#pragma unroll
    for (int ni = 0; ni < 4; ++ni) {
        const int p_loc = wc * 64 + ni * 16 + lr;
        pr4[ni] = clip1(prior[(size_t)b * 16384 + (size_t)nt * 128 + p_loc]);
    }
#pragma unroll
    for (int mi = 0; mi < 4; ++mi)
#pragma unroll
        for (int j = 0; j < 4; ++j) {
            const int o = wr * 64 + mi * 16 + lg * 4 + j;  // D row = o
            const float bov = bo[o];
            const size_t obase = ((size_t)b * 256 + o) * 16384 + (size_t)nt * 128;
#pragma unroll
            for (int ni = 0; ni < 4; ++ni) {
                const int p_loc = wc * 64 + ni * 16 + lr;  // D col = pixel
                out[obase + p_loc] =
                    x[obase + p_loc] + alpha * pr4[ni] + gamma * (acc[mi][ni][j] + bov);
            }
        }
}

extern "C" void kernel_launch(void* const* d_in, const int* in_sizes, int n_in,
                              void* d_out, int out_size, void* d_ws, size_t ws_size,
                              hipStream_t stream) {
    const float* x = (const float*)d_in[0];
    const float* prior = (const float*)d_in[1];
    const float* Wi = (const float*)d_in[2];
    const float* bi = (const float*)d_in[3];
    const float* A_param = (const float*)d_in[4];
    const float* B_param = (const float*)d_in[5];
    const float* alpha = (const float*)d_in[6];
    const float* gamma = (const float*)d_in[7];
    const float* Wo = (const float*)d_in[8];
    const float* bo = (const float*)d_in[9];
    float* out = (float*)d_out;

    u8* u8p = (u8*)d_ws;                             // 32 MiB fp8 u
    u8* hh8p = (u8*)d_ws + 33554432ull;              // 32 MiB fp8 hh
    u16* hf = (u16*)((char*)d_ws + 67108864ull);     // 64 MiB bf16 hf
    u16* Wib = (u16*)((char*)d_ws + 134217728ull);   // 128 KiB
    u16* Wob = (u16*)((char*)d_ws + 134348800ull);   // 128 KiB

    hipLaunchKernelGGL(kw_conv, dim3(256), dim3(256), 0, stream, Wi, Wo, Wib, Wob);
    hipLaunchKernelGGL(k01_gemm1, dim3(1024), dim3(512), 0, stream, x, prior, Wib, bi, B_param,
                       A_param, alpha, u8p, hh8p);
    hipLaunchKernelGGL(k2v, dim3(1024), dim3(256), 0, stream, u8p, hh8p, hf, A_param);
    hipLaunchKernelGGL(k3_gemm2, dim3(1024), dim3(512), 0, stream, hf, Wob, x, prior, bo,
                       alpha, gamma, out);
}